// Round 2
// baseline (439.510 us; speedup 1.0000x reference)
//
#include <hip/hip_runtime.h>

// Batched 128-point Walsh-Hadamard transform, scaled by 1/sqrt(128).
// W (input 1) is the deterministic Sylvester Hadamard matrix -> hardcoded FWHT.
//
// Layout: each thread holds 16 CONTIGUOUS floats (4x float4). A 64-lane wave
// covers 1024 floats = eight 128-blocks (8 lanes per block).
//   element-in-block e = 16*(lane&7) + c,  c in [0,16)
//   stages h=1,2,4,8   : intra-thread register butterflies
//   stage  h=16        : lane xor 1  -> DPP quad_perm [1,0,3,2] (VALU, no LDS)
//   stage  h=32        : lane xor 2  -> DPP quad_perm [2,3,0,1] (VALU, no LDS)
//   stage  h=64        : lane xor 4  -> ds_swizzle BitMode xor-4 (one LDS stage)
// This cuts cross-lane LDS round-trips from 5 (R1 kernel) to 1.

#define DPP_XOR1 0xB1  // quad_perm [1,0,3,2]
#define DPP_XOR2 0x4E  // quad_perm [2,3,0,1]
#define SWZ_XOR4 0x101F  // BitMode: (4<<10) | 0x1F

__device__ __forceinline__ float swz_xor4(float x) {
  return __int_as_float(__builtin_amdgcn_ds_swizzle(__float_as_int(x), SWZ_XOR4));
}

__global__ __launch_bounds__(256) void HadamardTransform_43722767073461_kernel(
    const float4* __restrict__ in, float4* __restrict__ out) {
  const int t    = blockIdx.x * 256 + threadIdx.x;
  const int lane = threadIdx.x & 63;

  const float4* p = in + (size_t)t * 4;
  float4 a0 = p[0];
  float4 a1 = p[1];
  float4 a2 = p[2];
  float4 a3 = p[3];

  float v[16] = {a0.x, a0.y, a0.z, a0.w, a1.x, a1.y, a1.z, a1.w,
                 a2.x, a2.y, a2.z, a2.w, a3.x, a3.y, a3.z, a3.w};

  // Intra-thread FWHT stages h = 1, 2, 4, 8 over 16 contiguous elements.
#pragma unroll
  for (int h = 1; h < 16; h <<= 1) {
#pragma unroll
    for (int i = 0; i < 16; i += 2 * h) {
#pragma unroll
      for (int j = i; j < i + h; ++j) {
        float a = v[j];
        float b = v[j + h];
        v[j]     = a + b;
        v[j + h] = a - b;
      }
    }
  }

  // Cross-lane stage h=16: partner = lane^1 (within quad), sign by (lane&1).
  {
    const float s = (lane & 1) ? -1.0f : 1.0f;
#pragma unroll
    for (int r = 0; r < 16; ++r) {
      float pr = __int_as_float(__builtin_amdgcn_update_dpp(
          __float_as_int(v[r]), __float_as_int(v[r]), DPP_XOR1, 0xF, 0xF, true));
      v[r] = fmaf(s, v[r], pr);
    }
  }

  // Cross-lane stage h=32: partner = lane^2 (within quad), sign by (lane&2).
  {
    const float s = (lane & 2) ? -1.0f : 1.0f;
#pragma unroll
    for (int r = 0; r < 16; ++r) {
      float pr = __int_as_float(__builtin_amdgcn_update_dpp(
          __float_as_int(v[r]), __float_as_int(v[r]), DPP_XOR2, 0xF, 0xF, true));
      v[r] = fmaf(s, v[r], pr);
    }
  }

  // Cross-lane stage h=64: partner = lane^4 -> one ds_swizzle stage.
  {
    const float s = (lane & 4) ? -1.0f : 1.0f;
    float pr[16];
#pragma unroll
    for (int r = 0; r < 16; ++r) pr[r] = swz_xor4(v[r]);
#pragma unroll
    for (int r = 0; r < 16; ++r) v[r] = fmaf(s, v[r], pr[r]);
  }

  const float scale = 0.08838834764831845f;  // 1/sqrt(128)
#pragma unroll
  for (int r = 0; r < 16; ++r) v[r] *= scale;

  float4* q = out + (size_t)t * 4;
  q[0] = make_float4(v[0], v[1], v[2], v[3]);
  q[1] = make_float4(v[4], v[5], v[6], v[7]);
  q[2] = make_float4(v[8], v[9], v[10], v[11]);
  q[3] = make_float4(v[12], v[13], v[14], v[15]);
}

extern "C" void kernel_launch(void* const* d_in, const int* in_sizes, int n_in,
                              void* d_out, int out_size, void* d_ws, size_t ws_size,
                              hipStream_t stream) {
  const float* x = (const float*)d_in[0];
  // d_in[1] (W) is the deterministic Hadamard matrix -- not needed.
  float* out = (float*)d_out;

  // out_size = 8192*8192 = 67,108,864 floats; 16 floats/thread ->
  // 4,194,304 threads -> 16384 blocks of 256 (exact, no tail).
  const int n_threads = out_size / 16;
  dim3 block(256);
  dim3 grid(n_threads / 256);
  hipLaunchKernelGGL(HadamardTransform_43722767073461_kernel, grid, block, 0, stream,
                     (const float4*)x, (float4*)out);
}